// Round 6
// baseline (480.457 us; speedup 1.0000x reference)
//
#include <hip/hip_runtime.h>
#include <hip/hip_bf16.h>

typedef __attribute__((ext_vector_type(8))) short short8;
typedef __attribute__((ext_vector_type(4))) float f32x4;

__device__ __forceinline__ float bf2f(unsigned short u) {
    union { unsigned int i; float f; } c;
    c.i = ((unsigned int)u) << 16;
    return c.f;
}
__device__ __forceinline__ unsigned short f2bf(float f) {
    union { float f; unsigned int i; } c;
    c.f = f;
    unsigned int x = c.i;
    x += 0x7FFFu + ((x >> 16) & 1u);
    return (unsigned short)(x >> 16);
}

// ---------------- fused GEMM: C[n,M] = f(A)[n,K] @ W[K,M] + bias ------------
// 64-row stripe per block. K<=256: stage ALL of A's K in LDS (16/32KB), then
// loop M/128 col-tiles (B -> registers per tile, C + stats per tile): A is
// fetched exactly once and per-block MFMA work scales with M.
// K=512: double-buffered 128-chunks (M=128 only).
// BN coeffs hoisted per-thread per-chunk (fixed 8 k-columns per thread).
// XF: 0=bf16 pass, 1=fp32 cast, 2=BN+GELU.
template<int K, int M, int XF>
__global__ __launch_bounds__(256, (K > 256) ? 4 : 5)
void gemmf_kernel(const void* __restrict__ Av,
                  const float* __restrict__ pSum, const float* __restrict__ pSq,
                  const float* __restrict__ pG, const float* __restrict__ pB,
                  const unsigned short* __restrict__ Wp,
                  const float* __restrict__ bias,
                  float* __restrict__ ssum, float* __restrict__ ssq,
                  unsigned short* __restrict__ C,
                  int nrows, float invN)
{
    constexpr int KS_TOT = K / 32;         // total k-steps
    constexpr int NKC    = K / 128;        // 128-wide k-chunks
    constexpr int NCT    = M / 128;        // col-tiles
    constexpr bool DBUF  = (K > 256);
    constexpr int NFRAG  = DBUF ? 32 : 4 * KS_TOT;
    __shared__ __align__(16) char smem[NFRAG * 1024];

    const int tid = threadIdx.x;
    const int l   = tid & 63, wv = tid >> 6;
    const int gr0 = blockIdx.x * 64;
    const int kq4 = l & 3, rloc = l >> 2;
    const int woff = ((kq4 * 16 + rloc) * 16) ^ (kq4 << 5);   // staging write (swizzled)
    const int loff = (l * 16) ^ ((l >> 4) << 5);              // frag read (swizzled)

    int rowg[4];
    #pragma unroll
    for (int i = 0; i < 4; ++i) {
        int rg = gr0 + i * 16 + rloc;
        rowg[i] = rg < nrows ? rg : nrows - 1;
    }

    f32x4 acc[4][2];
    short8 breg[2][4];

    auto loadB = [&](int ct, int kcb) {
        #pragma unroll
        for (int c = 0; c < 2; ++c) {
            const int col = ct * 128 + (wv * 2 + c) * 16 + (l & 15);
            const unsigned short* bp = Wp + (size_t)col * K + kcb + (l >> 4) * 8;
            #pragma unroll
            for (int ks = 0; ks < 4; ++ks)
                breg[c][ks] = *(const short8*)(bp + ks * 32);
        }
    };

    auto bncoef = [&](int c0k, float* sc8, float* sh8) {
        #pragma unroll
        for (int j = 0; j < 8; ++j) {
            const int c = c0k + j;
            const float mean = pSum[c] * invN;
            const float var  = pSq[c] * invN - mean * mean;
            const float sc   = pG[c] * rsqrtf(var + 1e-5f);
            sc8[j] = sc;
            sh8[j] = pB[c] - mean * sc;
        }
    };

    auto xf2 = [&](short8 t, const float* sc8, const float* sh8) -> short8 {
        short8 val;
        #pragma unroll
        for (int j = 0; j < 8; ++j) {
            float v = sc8[j] * bf2f((unsigned short)t[j]) + sh8[j];
            v = 0.5f * v * (1.0f + erff(v * 0.70710678118f));
            val[j] = (short)f2bf(v);
        }
        return val;
    };

    auto epilogue = [&](int ct) {
        const int lrow = l & 15, kg = l >> 4;
        #pragma unroll
        for (int c = 0; c < 2; ++c) {
            const int col = ct * 128 + (wv * 2 + c) * 16 + lrow;
            const float bc = bias[col];
            float s = 0.f, q = 0.f;
            #pragma unroll
            for (int r = 0; r < 4; ++r) {
                const int rb = gr0 + r * 16 + kg * 4;
                #pragma unroll
                for (int i = 0; i < 4; ++i) {
                    const int row = rb + i;
                    if (row < nrows) {
                        const float v = acc[r][c][i] + bc;
                        C[(size_t)row * M + col] = f2bf(v);
                        s += v; q += v * v;
                    }
                }
            }
            s += __shfl_xor(s, 16); s += __shfl_xor(s, 32);
            q += __shfl_xor(q, 16); q += __shfl_xor(q, 32);
            if (kg == 0 && ssum != nullptr) {
                atomicAdd(&ssum[col], s);
                atomicAdd(&ssq[col], q);
            }
        }
    };

    if constexpr (!DBUF) {
        // ---- stage ALL K chunks of the 64-row A panel ----
        #pragma unroll
        for (int h = 0; h < NKC; ++h) {
            const int kst = h * 4 + wv;                  // this thread's k-step
            const int c0k = kst * 32 + kq4 * 8;          // k-column base
            float sc8[8], sh8[8];
            if (XF == 2) bncoef(c0k, sc8, sh8);
            #pragma unroll
            for (int i = 0; i < 4; ++i) {
                const size_t eoff = (size_t)rowg[i] * K + c0k;
                short8 val;
                if (XF == 0) {
                    val = *(const short8*)((const unsigned short*)Av + eoff);
                } else if (XF == 1) {
                    const float* A = (const float*)Av;
                    f32x4 u0 = *(const f32x4*)(A + eoff);
                    f32x4 u1 = *(const f32x4*)(A + eoff + 4);
                    #pragma unroll
                    for (int j = 0; j < 4; ++j) {
                        val[j]     = (short)f2bf(u0[j]);
                        val[j + 4] = (short)f2bf(u1[j]);
                    }
                } else {
                    short8 t = *(const short8*)((const unsigned short*)Av + eoff);
                    val = xf2(t, sc8, sh8);
                }
                *(short8*)(smem + (i * KS_TOT + kst) * 1024 + woff) = val;
            }
        }
        __syncthreads();
        // ---- col-tile loop: B->regs, MFMA, epilogue ----
        #pragma unroll
        for (int ct = 0; ct < NCT; ++ct) {
            #pragma unroll
            for (int r = 0; r < 4; ++r)
                #pragma unroll
                for (int c = 0; c < 2; ++c) acc[r][c] = f32x4{0.f, 0.f, 0.f, 0.f};
            #pragma unroll
            for (int kc = 0; kc < NKC; ++kc) {
                loadB(ct, kc * 128);
                #pragma unroll
                for (int ks = 0; ks < 4; ++ks) {
                    const int ksg = kc * 4 + ks;
                    short8 af[4];
                    #pragma unroll
                    for (int r = 0; r < 4; ++r)
                        af[r] = *(const short8*)(smem + (r * KS_TOT + ksg) * 1024 + loff);
                    #pragma unroll
                    for (int r = 0; r < 4; ++r)
                        #pragma unroll
                        for (int c = 0; c < 2; ++c)
                            acc[r][c] = __builtin_amdgcn_mfma_f32_16x16x32_bf16(af[r], breg[c][ks], acc[r][c], 0, 0, 0);
                }
            }
            epilogue(ct);
        }
    } else {
        // ---- K=512, M=128: double-buffered 128-chunks ----
        const int akoff = wv * 32 + kq4 * 8;
        auto stageChunk = [&](int kcb, int b, const short8* pre) {
            const int c0k = kcb + akoff;
            float sc8[8], sh8[8];
            if (XF == 2) bncoef(c0k, sc8, sh8);
            #pragma unroll
            for (int i = 0; i < 4; ++i) {
                short8 t = pre ? pre[i]
                              : *(const short8*)((const unsigned short*)Av + (size_t)rowg[i] * K + c0k);
                short8 val = (XF == 2) ? xf2(t, sc8, sh8) : t;
                *(short8*)(smem + (b * 16 + i * 4 + wv) * 1024 + woff) = val;
            }
        };
        stageChunk(0, 0, nullptr);
        __syncthreads();
        #pragma unroll
        for (int r = 0; r < 4; ++r)
            #pragma unroll
            for (int c = 0; c < 2; ++c) acc[r][c] = f32x4{0.f, 0.f, 0.f, 0.f};
        #pragma unroll
        for (int kc = 0; kc < NKC; ++kc) {
            const int cur = kc & 1;
            loadB(0, kc * 128);
            short8 anext[4];
            if (kc + 1 < NKC) {
                const int c0k = (kc + 1) * 128 + akoff;
                #pragma unroll
                for (int i = 0; i < 4; ++i)
                    anext[i] = *(const short8*)((const unsigned short*)Av + (size_t)rowg[i] * K + c0k);
            }
            #pragma unroll
            for (int ks = 0; ks < 4; ++ks) {
                short8 af[4];
                #pragma unroll
                for (int r = 0; r < 4; ++r)
                    af[r] = *(const short8*)(smem + (cur * 16 + r * 4 + ks) * 1024 + loff);
                #pragma unroll
                for (int r = 0; r < 4; ++r)
                    #pragma unroll
                    for (int c = 0; c < 2; ++c)
                        acc[r][c] = __builtin_amdgcn_mfma_f32_16x16x32_bf16(af[r], breg[c][ks], acc[r][c], 0, 0, 0);
            }
            if (kc + 1 < NKC) {
                stageChunk((kc + 1) * 128, cur ^ 1, anext);
                __syncthreads();
            }
        }
        epilogue(0);
    }
}

// ---------------- h3 = bn(t4) + t2 + x (bf16) -------------------------------
__global__ void h3_kernel(const unsigned short* __restrict__ t4,
                          const float* __restrict__ pSum, const float* __restrict__ pSq,
                          const float* __restrict__ pG, const float* __restrict__ pB,
                          const unsigned short* __restrict__ t2,
                          const float* __restrict__ xr,
                          unsigned short* __restrict__ H3, float invN, int total4)
{
    int idx = blockIdx.x * blockDim.x + threadIdx.x;
    if (idx >= total4) return;
    const int base = idx * 4;
    const int c0 = base & 127;
    ushort4 tv = *(const ushort4*)(t4 + base);
    ushort4 uv = *(const ushort4*)(t2 + base);
    float4  xv = *(const float4*)(xr + base);
    unsigned short ts[4] = {tv.x, tv.y, tv.z, tv.w};
    unsigned short us[4] = {uv.x, uv.y, uv.z, uv.w};
    const float* px = &xv.x;
    ushort4 ov;
    unsigned short* po = &ov.x;
    #pragma unroll
    for (int j = 0; j < 4; ++j) {
        const int c = c0 + j;
        const float mean = pSum[c] * invN;
        const float var  = pSq[c] * invN - mean * mean;
        const float sc   = pG[c] * rsqrtf(var + 1e-5f);
        const float sh   = pB[c] - mean * sc;
        po[j] = f2bf(sc * bf2f(ts[j]) + sh + bf2f(us[j]) + px[j]);
    }
    *(ushort4*)(H3 + base) = ov;
}

// ---------------- CSR build ------------------------------------------------
__global__ void hist_kernel(const int* __restrict__ ei, int* __restrict__ cnt, int E)
{
    int e = blockIdx.x * blockDim.x + threadIdx.x;
    if (e < E) atomicAdd(&cnt[ei[E + e]], 1);
}

__global__ void scan_reduce(const int* __restrict__ cnt, int* __restrict__ blksum, int n)
{
    __shared__ int s[256];
    int t = threadIdx.x;
    int i = blockIdx.x * 256 + t;
    s[t] = i < n ? cnt[i] : 0;
    __syncthreads();
    for (int d = 128; d > 0; d >>= 1) {
        if (t < d) s[t] += s[t + d];
        __syncthreads();
    }
    if (t == 0) blksum[blockIdx.x] = s[0];
}

__global__ void scan_top(int* __restrict__ blksum, int nb)
{
    __shared__ int s[256];
    int t = threadIdx.x;
    int v = t < nb ? blksum[t] : 0;
    s[t] = v;
    __syncthreads();
    for (int d = 1; d < 256; d <<= 1) {
        int u = (t >= d) ? s[t - d] : 0;
        __syncthreads();
        s[t] += u;
        __syncthreads();
    }
    if (t < nb) blksum[t] = s[t] - v;   // exclusive
}

__global__ void scan_apply(const int* __restrict__ cnt, const int* __restrict__ blksum,
                           int* __restrict__ offs, int* __restrict__ cursor, int n)
{
    __shared__ int s[256];
    int t = threadIdx.x;
    int i = blockIdx.x * 256 + t;
    int v = i < n ? cnt[i] : 0;
    s[t] = v;
    __syncthreads();
    for (int d = 1; d < 256; d <<= 1) {
        int u = (t >= d) ? s[t - d] : 0;
        __syncthreads();
        s[t] += u;
        __syncthreads();
    }
    int excl = s[t] - v + blksum[blockIdx.x];
    if (i < n) { offs[i] = excl; cursor[i] = excl; }
}

__global__ void place_kernel(const int* __restrict__ ei, int* __restrict__ cursor,
                             int* __restrict__ ssrc, int E)
{
    int e = blockIdx.x * blockDim.x + threadIdx.x;
    if (e < E) {
        int pos = atomicAdd(&cursor[ei[E + e]], 1);
        ssrc[pos] = ei[e];
    }
}

// ---------------- GIN gather with fused BN0 --------------------------------
__global__ __launch_bounds__(256)
void gather_kernel(const unsigned short* __restrict__ T0,
                   const float* __restrict__ pSum, const float* __restrict__ pSq,
                   const float* __restrict__ pG, const float* __restrict__ pB,
                   float invN,
                   const int* __restrict__ ssrc, const int* __restrict__ offs,
                   const int* __restrict__ cnt,
                   unsigned short* __restrict__ Zb, int N)
{
    const int wave = threadIdx.x >> 6;
    const int lane = threadIdx.x & 63;
    const int node = blockIdx.x * 4 + wave;
    if (node >= N) return;

    unsigned int hv = *(const unsigned int*)(T0 + (size_t)node * 128 + lane * 2);
    float a0 = bf2f((unsigned short)hv);
    float a1 = bf2f((unsigned short)(hv >> 16));

    const int off = offs[node];
    const int deg = cnt[node];
    for (int base = 0; base < deg; base += 64) {
        int m = deg - base;
        if (m > 64) m = 64;
        int idx = (base + lane < deg) ? ssrc[off + base + lane] : 0;
        int k = 0;
        for (; k + 1 < m; k += 2) {
            int s0 = __shfl(idx, k);
            int s1 = __shfl(idx, k + 1);
            unsigned int v0 = *(const unsigned int*)(T0 + (size_t)s0 * 128 + lane * 2);
            unsigned int v1 = *(const unsigned int*)(T0 + (size_t)s1 * 128 + lane * 2);
            a0 += bf2f((unsigned short)v0) + bf2f((unsigned short)v1);
            a1 += bf2f((unsigned short)(v0 >> 16)) + bf2f((unsigned short)(v1 >> 16));
        }
        if (k < m) {
            int s0 = __shfl(idx, k);
            unsigned int v0 = *(const unsigned int*)(T0 + (size_t)s0 * 128 + lane * 2);
            a0 += bf2f((unsigned short)v0);
            a1 += bf2f((unsigned short)(v0 >> 16));
        }
    }
    const int c0 = lane * 2;
    const float mean0 = pSum[c0] * invN;
    const float var0  = pSq[c0] * invN - mean0 * mean0;
    const float sc0   = pG[c0] * rsqrtf(var0 + 1e-5f);
    const float sh0   = pB[c0] - mean0 * sc0;
    const float mean1 = pSum[c0 + 1] * invN;
    const float var1  = pSq[c0 + 1] * invN - mean1 * mean1;
    const float sc1   = pG[c0 + 1] * rsqrtf(var1 + 1e-5f);
    const float sh1   = pB[c0 + 1] - mean1 * sc1;
    const float dp1 = (float)(deg + 1);
    const float z0 = sc0 * a0 + dp1 * sh0;
    const float z1 = sc1 * a1 + dp1 * sh1;
    unsigned int o = ((unsigned int)f2bf(z1) << 16) | (unsigned int)f2bf(z0);
    *(unsigned int*)(Zb + (size_t)node * 128 + lane * 2) = o;
}

// ---------------- final: out = bn(t6) + h3 (fp32) --------------------------
__global__ void final_kernel(const unsigned short* __restrict__ t6,
                             const float* __restrict__ pSum, const float* __restrict__ pSq,
                             const float* __restrict__ pG, const float* __restrict__ pB,
                             const unsigned short* __restrict__ h3,
                             float* __restrict__ out, float invN, int total4)
{
    int idx = blockIdx.x * blockDim.x + threadIdx.x;
    if (idx >= total4) return;
    const int base = idx * 4;
    const int c0 = base & 127;
    ushort4 tv = *(const ushort4*)(t6 + base);
    ushort4 hv = *(const ushort4*)(h3 + base);
    unsigned short ts[4] = {tv.x, tv.y, tv.z, tv.w};
    unsigned short hs[4] = {hv.x, hv.y, hv.z, hv.w};
    float4 ov;
    float* po = &ov.x;
    #pragma unroll
    for (int j = 0; j < 4; ++j) {
        const int c = c0 + j;
        const float mean = pSum[c] * invN;
        const float var  = pSq[c] * invN - mean * mean;
        const float sc   = pG[c] * rsqrtf(var + 1e-5f);
        const float sh   = pB[c] - mean * sc;
        po[j] = sc * bf2f(ts[j]) + sh + bf2f(hs[j]);
    }
    *(float4*)(out + base) = ov;
}

// ---------------- weight pack: Wp[m][k] = bf16(W[k][m]) ---------------------
struct PackDesc { const float* src; unsigned short* dst; int K; int M; };
struct Pack7 { PackDesc d[7]; };
__global__ void pack_kernel(Pack7 p)
{
    PackDesc d = p.d[blockIdx.y];
    const int total = d.K * d.M;
    for (int idx = blockIdx.x * blockDim.x + threadIdx.x; idx < total;
         idx += gridDim.x * blockDim.x) {
        const int k = idx / d.M;
        const int m = idx - k * d.M;
        d.dst[(size_t)m * d.K + k] = f2bf(d.src[idx]);
    }
}

extern "C" void kernel_launch(void* const* d_in, const int* in_sizes, int n_in,
                              void* d_out, int out_size, void* d_ws, size_t ws_size,
                              hipStream_t stream)
{
    const float* x     = (const float*)d_in[0];
    const int*   ei    = (const int*)d_in[1];
    const float* enc_W = (const float*)d_in[2];
    const float* enc_b = (const float*)d_in[3];
    const float* bn_g  = (const float*)d_in[4];
    const float* bn_b  = (const float*)d_in[5];
    const float* gW1   = (const float*)d_in[6];
    const float* gb1   = (const float*)d_in[7];
    const float* gg    = (const float*)d_in[8];
    const float* gbb   = (const float*)d_in[9];
    const float* gW2   = (const float*)d_in[10];
    const float* gb2   = (const float*)d_in[11];
    const float* f2W1  = (const float*)d_in[12];
    const float* f2b1  = (const float*)d_in[13];
    const float* f2g1  = (const float*)d_in[14];
    const float* f2bb1 = (const float*)d_in[15];
    const float* f2W2  = (const float*)d_in[16];
    const float* f2b2  = (const float*)d_in[17];
    const float* f2g2  = (const float*)d_in[18];
    const float* f2bb2 = (const float*)d_in[19];
    const float* fnW1  = (const float*)d_in[20];
    const float* fnb1  = (const float*)d_in[21];
    const float* fng1  = (const float*)d_in[22];
    const float* fnbb1 = (const float*)d_in[23];
    const float* fnW2  = (const float*)d_in[24];
    const float* fnb2  = (const float*)d_in[25];
    const float* fng2  = (const float*)d_in[26];
    const float* fnbb2 = (const float*)d_in[27];

    const int D = 128;
    const int N = in_sizes[0] / D;   // 50000
    const int E = in_sizes[1] / 2;   // 640000
    const float invN = 1.0f / (float)N;

    // ---- workspace layout ----
    char* w = (char*)d_ws;
    float* s0 = (float*)w;          // [sum(128) | sq(128)]
    float* s1 = s0 + 256;
    float* s3 = s1 + 256;           // [sum(256) | sq(256)]
    float* s4 = s3 + 512;
    float* s5 = s4 + 256;           // [sum(512) | sq(512)]
    float* s6 = s5 + 1024;
    const size_t statsBytes = 2560 * sizeof(float);
    size_t off = statsBytes;

    unsigned short* wpE  = (unsigned short*)(w + off); off += (size_t)128 * 128 * 2;
    unsigned short* wpG1 = (unsigned short*)(w + off); off += (size_t)128 * 128 * 2;
    unsigned short* wpG2 = (unsigned short*)(w + off); off += (size_t)128 * 128 * 2;
    unsigned short* wpF1 = (unsigned short*)(w + off); off += (size_t)128 * 256 * 2;
    unsigned short* wpF2 = (unsigned short*)(w + off); off += (size_t)256 * 128 * 2;
    unsigned short* wpN1 = (unsigned short*)(w + off); off += (size_t)128 * 512 * 2;
    unsigned short* wpN2 = (unsigned short*)(w + off); off += (size_t)512 * 128 * 2;

    unsigned short* P1 = (unsigned short*)(w + off); off += (size_t)N * 128 * 2; // t0,t1,t4,t6
    unsigned short* Zb = (unsigned short*)(w + off); off += (size_t)N * 128 * 2; // Z, t2
    unsigned short* H3 = (unsigned short*)(w + off); off += (size_t)N * 128 * 2; // h3
    unsigned short* T3 = (unsigned short*)(w + off); off += (size_t)N * 256 * 2; // t3
    unsigned short* T5 = (unsigned short*)(w + off); off += (size_t)N * 512 * 2; // t5

    // CSR arrays inside T5 (CSR dead after gather; T5 first written later)
    const int NB = (N + 255) / 256;
    char* csr = (char*)T5;
    int* cnt    = (int*)csr;  csr += (size_t)NB * 256 * 4;
    int* offs   = (int*)csr;  csr += (size_t)NB * 256 * 4;
    int* cursor = (int*)csr;  csr += (size_t)NB * 256 * 4;
    int* blksum = (int*)csr;  csr += 1024;
    int* ssrc   = (int*)csr;

    hipMemsetAsync(d_ws, 0, statsBytes, stream);
    hipMemsetAsync(cnt, 0, (size_t)NB * 256 * 4, stream);

    Pack7 pk;
    pk.d[0] = PackDesc{enc_W, wpE, 128, 128};
    pk.d[1] = PackDesc{gW1, wpG1, 128, 128};
    pk.d[2] = PackDesc{gW2, wpG2, 128, 128};
    pk.d[3] = PackDesc{f2W1, wpF1, 128, 256};
    pk.d[4] = PackDesc{f2W2, wpF2, 256, 128};
    pk.d[5] = PackDesc{fnW1, wpN1, 128, 512};
    pk.d[6] = PackDesc{fnW2, wpN2, 512, 128};
    pack_kernel<<<dim3(64, 7), 256, 0, stream>>>(pk);

    const int eb = (E + 255) / 256;
    hist_kernel<<<eb, 256, 0, stream>>>(ei, cnt, E);
    scan_reduce<<<NB, 256, 0, stream>>>(cnt, blksum, N);
    scan_top<<<1, 256, 0, stream>>>(blksum, NB);
    scan_apply<<<NB, 256, 0, stream>>>(cnt, blksum, offs, cursor, N);
    place_kernel<<<eb, 256, 0, stream>>>(ei, cursor, ssrc, E);

    const int rb  = (N + 63) / 64;
    const int t4a = N * 128 / 4;
    const int ewb = (t4a + 255) / 256;

    // 1) t0 = x @ encW + enc_b                       -> P1, stats s0
    gemmf_kernel<128, 128, 1><<<rb, 256, 0, stream>>>(
        x, nullptr, nullptr, nullptr, nullptr,
        wpE, enc_b, s0, s0 + 128, P1, N, invN);
    // 2) Z = bn0(t0 self+agg)                        -> Zb
    gather_kernel<<<(N + 3) / 4, 256, 0, stream>>>(
        P1, s0, s0 + 128, bn_g, bn_b, invN, ssrc, offs, cnt, Zb, N);
    // 3) t1 = Z @ gW1 + gb1                          -> P1, stats s1
    gemmf_kernel<128, 128, 0><<<rb, 256, 0, stream>>>(
        Zb, nullptr, nullptr, nullptr, nullptr,
        wpG1, gb1, s1, s1 + 128, P1, N, invN);
    // 4) t2 = gelu(bn(t1)) @ gW2 + gb2               -> Zb (no stats)
    gemmf_kernel<128, 128, 2><<<rb, 256, 0, stream>>>(
        P1, s1, s1 + 128, gg, gbb,
        wpG2, gb2, nullptr, nullptr, Zb, N, invN);
    // 5) t3 = t2 @ f2W1 + f2b1                       -> T3 [N,256], stats s3
    gemmf_kernel<128, 256, 0><<<rb, 256, 0, stream>>>(
        Zb, nullptr, nullptr, nullptr, nullptr,
        wpF1, f2b1, s3, s3 + 256, T3, N, invN);
    // 6) t4 = gelu(bn(t3)) @ f2W2 + f2b2             -> P1, stats s4
    gemmf_kernel<256, 128, 2><<<rb, 256, 0, stream>>>(
        T3, s3, s3 + 256, f2g1, f2bb1,
        wpF2, f2b2, s4, s4 + 128, P1, N, invN);
    // 7) h3 = bn(t4) + t2 + x                        -> H3 (bf16, once)
    h3_kernel<<<ewb, 256, 0, stream>>>(
        P1, s4, s4 + 128, f2g2, f2bb2, Zb, x, H3, invN, t4a);
    // 8) t5 = h3 @ fnW1 + fnb1                       -> T5 [N,512], stats s5
    gemmf_kernel<128, 512, 0><<<rb, 256, 0, stream>>>(
        H3, nullptr, nullptr, nullptr, nullptr,
        wpN1, fnb1, s5, s5 + 512, T5, N, invN);
    // 9) t6 = gelu(bn(t5)) @ fnW2 + fnb2             -> P1, stats s6
    gemmf_kernel<512, 128, 2><<<rb, 256, 0, stream>>>(
        T5, s5, s5 + 512, fng1, fnbb1,
        wpN2, fnb2, s6, s6 + 128, P1, N, invN);
    // 10) out = bn(t6) + h3                           -> d_out (fp32)
    final_kernel<<<ewb, 256, 0, stream>>>(
        P1, s6, s6 + 128, fng2, fnbb2, H3, (float*)d_out, invN, t4a);

    (void)n_in; (void)out_size; (void)ws_size;
}

// Round 7
// 437.195 us; speedup vs baseline: 1.0990x; 1.0990x over previous
//
#include <hip/hip_runtime.h>
#include <hip/hip_bf16.h>

typedef __attribute__((ext_vector_type(8))) short short8;
typedef __attribute__((ext_vector_type(4))) float f32x4;

__device__ __forceinline__ float bf2f(unsigned short u) {
    union { unsigned int i; float f; } c;
    c.i = ((unsigned int)u) << 16;
    return c.f;
}
__device__ __forceinline__ unsigned short f2bf(float f) {
    union { float f; unsigned int i; } c;
    c.f = f;
    unsigned int x = c.i;
    x += 0x7FFFu + ((x >> 16) & 1u);
    return (unsigned short)(x >> 16);
}

// ---------------- fused GEMM: C[n,M] = f(A)[n,K] @ W[K,M] + bias ------------
// 64-row stripe per block. K<=256: stage ALL of A's K in LDS, then loop M/128
// col-tiles (B->registers per tile). K=512: double-buffered 128-chunks (M=128).
// Epilogue: acc -> LDS (XOR-swizzled) -> fully-coalesced short8 row stores
// (fixes partial-sector write amplification seen in R6: WRITE 2.6x logical).
// XF: 0=bf16 pass, 1=fp32 cast, 2=BN+GELU.
template<int K, int M, int XF>
__global__ __launch_bounds__(256, (K > 256) ? 4 : 5)
void gemmf_kernel(const void* __restrict__ Av,
                  const float* __restrict__ pSum, const float* __restrict__ pSq,
                  const float* __restrict__ pG, const float* __restrict__ pB,
                  const unsigned short* __restrict__ Wp,
                  const float* __restrict__ bias,
                  float* __restrict__ ssum, float* __restrict__ ssq,
                  unsigned short* __restrict__ C,
                  int nrows, float invN)
{
    constexpr int KS_TOT = K / 32;         // total k-steps
    constexpr int NKC    = K / 128;        // 128-wide k-chunks
    constexpr int NCT    = M / 128;        // col-tiles
    constexpr bool DBUF  = (K > 256);
    constexpr int NFRAG  = DBUF ? 32 : 4 * KS_TOT;
    // C-staging buffer: reuse A region when single col-tile (A dead after MFMA),
    // else a dedicated 16KB region.
    __shared__ __align__(16) char smem[NFRAG * 1024 + ((NCT > 1) ? 16384 : 0)];
    char* cbuf = smem + ((NCT > 1) ? NFRAG * 1024 : 0);

    const int tid = threadIdx.x;
    const int l   = tid & 63, wv = tid >> 6;
    const int gr0 = blockIdx.x * 64;
    const int kq4 = l & 3, rloc = l >> 2;
    const int woff = ((kq4 * 16 + rloc) * 16) ^ (kq4 << 5);   // staging write (swizzled)
    const int loff = (l * 16) ^ ((l >> 4) << 5);              // frag read (swizzled)

    int rowg[4];
    #pragma unroll
    for (int i = 0; i < 4; ++i) {
        int rg = gr0 + i * 16 + rloc;
        rowg[i] = rg < nrows ? rg : nrows - 1;
    }

    f32x4 acc[4][2];
    short8 breg[2][4];

    auto loadB = [&](int ct, int kcb) {
        #pragma unroll
        for (int c = 0; c < 2; ++c) {
            const int col = ct * 128 + (wv * 2 + c) * 16 + (l & 15);
            const unsigned short* bp = Wp + (size_t)col * K + kcb + (l >> 4) * 8;
            #pragma unroll
            for (int ks = 0; ks < 4; ++ks)
                breg[c][ks] = *(const short8*)(bp + ks * 32);
        }
    };

    auto bncoef = [&](int c0k, float* sc8, float* sh8) {
        #pragma unroll
        for (int j = 0; j < 8; ++j) {
            const int c = c0k + j;
            const float mean = pSum[c] * invN;
            const float var  = pSq[c] * invN - mean * mean;
            const float sc   = pG[c] * rsqrtf(var + 1e-5f);
            sc8[j] = sc;
            sh8[j] = pB[c] - mean * sc;
        }
    };

    auto xf2 = [&](short8 t, const float* sc8, const float* sh8) -> short8 {
        short8 val;
        #pragma unroll
        for (int j = 0; j < 8; ++j) {
            float v = sc8[j] * bf2f((unsigned short)t[j]) + sh8[j];
            v = 0.5f * v * (1.0f + erff(v * 0.70710678118f));
            val[j] = (short)f2bf(v);
        }
        return val;
    };

    // Epilogue: stats + LDS-staged coalesced C stores.
    auto epilogue = [&](int ct) {
        const int lrow = l & 15, kg = l >> 4;
        __syncthreads();   // prior readers of cbuf (or A-region) done
        #pragma unroll
        for (int c = 0; c < 2; ++c) {
            const int col  = (wv * 2 + c) * 16 + lrow;     // col within tile
            const int gcol = ct * 128 + col;
            const float bc = bias[gcol];
            float s = 0.f, q = 0.f;
            #pragma unroll
            for (int r = 0; r < 4; ++r) {
                #pragma unroll
                for (int i = 0; i < 4; ++i) {
                    const int rl = r * 16 + kg * 4 + i;    // row within tile
                    const float v = acc[r][c][i] + bc;
                    if (gr0 + rl < nrows) { s += v; q += v * v; }
                    const int byte = rl * 256 + ((col * 2) ^ ((rl & 7) << 4));
                    *(unsigned short*)(cbuf + byte) = f2bf(v);
                }
            }
            s += __shfl_xor(s, 16); s += __shfl_xor(s, 32);
            q += __shfl_xor(q, 16); q += __shfl_xor(q, 32);
            if (kg == 0 && ssum != nullptr) {
                atomicAdd(&ssum[gcol], s);
                atomicAdd(&ssq[gcol], q);
            }
        }
        __syncthreads();
        // 64 rows x 256B, 16 lanes per row -> fully coalesced
        #pragma unroll
        for (int j = 0; j < 4; ++j) {
            const int lin = j * 256 + tid;
            const int rl = lin >> 4, chunk = lin & 15;
            const int row = gr0 + rl;
            if (row < nrows) {
                short8 vv = *(const short8*)(cbuf + rl * 256 + ((chunk * 16) ^ ((rl & 7) << 4)));
                *(short8*)(C + (size_t)row * M + ct * 128 + chunk * 8) = vv;
            }
        }
    };

    if constexpr (!DBUF) {
        // ---- stage ALL K chunks of the 64-row A panel ----
        #pragma unroll
        for (int h = 0; h < NKC; ++h) {
            const int kst = h * 4 + wv;                  // this thread's k-step
            const int c0k = kst * 32 + kq4 * 8;          // k-column base
            float sc8[8], sh8[8];
            if (XF == 2) bncoef(c0k, sc8, sh8);
            #pragma unroll
            for (int i = 0; i < 4; ++i) {
                const size_t eoff = (size_t)rowg[i] * K + c0k;
                short8 val;
                if (XF == 0) {
                    val = *(const short8*)((const unsigned short*)Av + eoff);
                } else if (XF == 1) {
                    const float* A = (const float*)Av;
                    f32x4 u0 = *(const f32x4*)(A + eoff);
                    f32x4 u1 = *(const f32x4*)(A + eoff + 4);
                    #pragma unroll
                    for (int j = 0; j < 4; ++j) {
                        val[j]     = (short)f2bf(u0[j]);
                        val[j + 4] = (short)f2bf(u1[j]);
                    }
                } else {
                    short8 t = *(const short8*)((const unsigned short*)Av + eoff);
                    val = xf2(t, sc8, sh8);
                }
                *(short8*)(smem + (i * KS_TOT + kst) * 1024 + woff) = val;
            }
        }
        __syncthreads();
        // ---- col-tile loop: B->regs, MFMA, epilogue ----
        #pragma unroll
        for (int ct = 0; ct < NCT; ++ct) {
            #pragma unroll
            for (int r = 0; r < 4; ++r)
                #pragma unroll
                for (int c = 0; c < 2; ++c) acc[r][c] = f32x4{0.f, 0.f, 0.f, 0.f};
            #pragma unroll
            for (int kc = 0; kc < NKC; ++kc) {
                loadB(ct, kc * 128);
                #pragma unroll
                for (int ks = 0; ks < 4; ++ks) {
                    const int ksg = kc * 4 + ks;
                    short8 af[4];
                    #pragma unroll
                    for (int r = 0; r < 4; ++r)
                        af[r] = *(const short8*)(smem + (r * KS_TOT + ksg) * 1024 + loff);
                    #pragma unroll
                    for (int r = 0; r < 4; ++r)
                        #pragma unroll
                        for (int c = 0; c < 2; ++c)
                            acc[r][c] = __builtin_amdgcn_mfma_f32_16x16x32_bf16(af[r], breg[c][ks], acc[r][c], 0, 0, 0);
                }
            }
            epilogue(ct);
        }
    } else {
        // ---- K=512, M=128: double-buffered 128-chunks ----
        const int akoff = wv * 32 + kq4 * 8;
        auto stageChunk = [&](int kcb, int b, const short8* pre) {
            const int c0k = kcb + akoff;
            float sc8[8], sh8[8];
            if (XF == 2) bncoef(c0k, sc8, sh8);
            #pragma unroll
            for (int i = 0; i < 4; ++i) {
                short8 t = pre ? pre[i]
                              : *(const short8*)((const unsigned short*)Av + (size_t)rowg[i] * K + c0k);
                short8 val = (XF == 2) ? xf2(t, sc8, sh8) : t;
                *(short8*)(smem + (b * 16 + i * 4 + wv) * 1024 + woff) = val;
            }
        };
        stageChunk(0, 0, nullptr);
        __syncthreads();
        #pragma unroll
        for (int r = 0; r < 4; ++r)
            #pragma unroll
            for (int c = 0; c < 2; ++c) acc[r][c] = f32x4{0.f, 0.f, 0.f, 0.f};
        #pragma unroll
        for (int kc = 0; kc < NKC; ++kc) {
            const int cur = kc & 1;
            loadB(0, kc * 128);
            short8 anext[4];
            if (kc + 1 < NKC) {
                const int c0k = (kc + 1) * 128 + akoff;
                #pragma unroll
                for (int i = 0; i < 4; ++i)
                    anext[i] = *(const short8*)((const unsigned short*)Av + (size_t)rowg[i] * K + c0k);
            }
            #pragma unroll
            for (int ks = 0; ks < 4; ++ks) {
                short8 af[4];
                #pragma unroll
                for (int r = 0; r < 4; ++r)
                    af[r] = *(const short8*)(smem + (cur * 16 + r * 4 + ks) * 1024 + loff);
                #pragma unroll
                for (int r = 0; r < 4; ++r)
                    #pragma unroll
                    for (int c = 0; c < 2; ++c)
                        acc[r][c] = __builtin_amdgcn_mfma_f32_16x16x32_bf16(af[r], breg[c][ks], acc[r][c], 0, 0, 0);
            }
            if (kc + 1 < NKC) {
                stageChunk((kc + 1) * 128, cur ^ 1, anext);
                __syncthreads();
            }
        }
        epilogue(0);
    }
}

// ---------------- h3 = bn(t4) + t2 + x (bf16) -------------------------------
__global__ void h3_kernel(const unsigned short* __restrict__ t4,
                          const float* __restrict__ pSum, const float* __restrict__ pSq,
                          const float* __restrict__ pG, const float* __restrict__ pB,
                          const unsigned short* __restrict__ t2,
                          const float* __restrict__ xr,
                          unsigned short* __restrict__ H3, float invN, int total4)
{
    int idx = blockIdx.x * blockDim.x + threadIdx.x;
    if (idx >= total4) return;
    const int base = idx * 4;
    const int c0 = base & 127;
    ushort4 tv = *(const ushort4*)(t4 + base);
    ushort4 uv = *(const ushort4*)(t2 + base);
    float4  xv = *(const float4*)(xr + base);
    unsigned short ts[4] = {tv.x, tv.y, tv.z, tv.w};
    unsigned short us[4] = {uv.x, uv.y, uv.z, uv.w};
    const float* px = &xv.x;
    ushort4 ov;
    unsigned short* po = &ov.x;
    #pragma unroll
    for (int j = 0; j < 4; ++j) {
        const int c = c0 + j;
        const float mean = pSum[c] * invN;
        const float var  = pSq[c] * invN - mean * mean;
        const float sc   = pG[c] * rsqrtf(var + 1e-5f);
        const float sh   = pB[c] - mean * sc;
        po[j] = f2bf(sc * bf2f(ts[j]) + sh + bf2f(us[j]) + px[j]);
    }
    *(ushort4*)(H3 + base) = ov;
}

// ---------------- CSR build ------------------------------------------------
__global__ void hist_kernel(const int* __restrict__ ei, int* __restrict__ cnt, int E)
{
    int e = blockIdx.x * blockDim.x + threadIdx.x;
    if (e < E) atomicAdd(&cnt[ei[E + e]], 1);
}

__global__ void scan_reduce(const int* __restrict__ cnt, int* __restrict__ blksum, int n)
{
    __shared__ int s[256];
    int t = threadIdx.x;
    int i = blockIdx.x * 256 + t;
    s[t] = i < n ? cnt[i] : 0;
    __syncthreads();
    for (int d = 128; d > 0; d >>= 1) {
        if (t < d) s[t] += s[t + d];
        __syncthreads();
    }
    if (t == 0) blksum[blockIdx.x] = s[0];
}

__global__ void scan_top(int* __restrict__ blksum, int nb)
{
    __shared__ int s[256];
    int t = threadIdx.x;
    int v = t < nb ? blksum[t] : 0;
    s[t] = v;
    __syncthreads();
    for (int d = 1; d < 256; d <<= 1) {
        int u = (t >= d) ? s[t - d] : 0;
        __syncthreads();
        s[t] += u;
        __syncthreads();
    }
    if (t < nb) blksum[t] = s[t] - v;   // exclusive
}

__global__ void scan_apply(const int* __restrict__ cnt, const int* __restrict__ blksum,
                           int* __restrict__ offs, int* __restrict__ cursor, int n)
{
    __shared__ int s[256];
    int t = threadIdx.x;
    int i = blockIdx.x * 256 + t;
    int v = i < n ? cnt[i] : 0;
    s[t] = v;
    __syncthreads();
    for (int d = 1; d < 256; d <<= 1) {
        int u = (t >= d) ? s[t - d] : 0;
        __syncthreads();
        s[t] += u;
        __syncthreads();
    }
    int excl = s[t] - v + blksum[blockIdx.x];
    if (i < n) { offs[i] = excl; cursor[i] = excl; }
}

__global__ void place_kernel(const int* __restrict__ ei, int* __restrict__ cursor,
                             int* __restrict__ ssrc, int E)
{
    int e = blockIdx.x * blockDim.x + threadIdx.x;
    if (e < E) {
        int pos = atomicAdd(&cursor[ei[E + e]], 1);
        ssrc[pos] = ei[e];
    }
}

// ---------------- GIN gather with fused BN0 --------------------------------
__global__ __launch_bounds__(256)
void gather_kernel(const unsigned short* __restrict__ T0,
                   const float* __restrict__ pSum, const float* __restrict__ pSq,
                   const float* __restrict__ pG, const float* __restrict__ pB,
                   float invN,
                   const int* __restrict__ ssrc, const int* __restrict__ offs,
                   const int* __restrict__ cnt,
                   unsigned short* __restrict__ Zb, int N)
{
    const int wave = threadIdx.x >> 6;
    const int lane = threadIdx.x & 63;
    const int node = blockIdx.x * 4 + wave;
    if (node >= N) return;

    unsigned int hv = *(const unsigned int*)(T0 + (size_t)node * 128 + lane * 2);
    float a0 = bf2f((unsigned short)hv);
    float a1 = bf2f((unsigned short)(hv >> 16));

    const int off = offs[node];
    const int deg = cnt[node];
    for (int base = 0; base < deg; base += 64) {
        int m = deg - base;
        if (m > 64) m = 64;
        int idx = (base + lane < deg) ? ssrc[off + base + lane] : 0;
        int k = 0;
        for (; k + 1 < m; k += 2) {
            int s0 = __shfl(idx, k);
            int s1 = __shfl(idx, k + 1);
            unsigned int v0 = *(const unsigned int*)(T0 + (size_t)s0 * 128 + lane * 2);
            unsigned int v1 = *(const unsigned int*)(T0 + (size_t)s1 * 128 + lane * 2);
            a0 += bf2f((unsigned short)v0) + bf2f((unsigned short)v1);
            a1 += bf2f((unsigned short)(v0 >> 16)) + bf2f((unsigned short)(v1 >> 16));
        }
        if (k < m) {
            int s0 = __shfl(idx, k);
            unsigned int v0 = *(const unsigned int*)(T0 + (size_t)s0 * 128 + lane * 2);
            a0 += bf2f((unsigned short)v0);
            a1 += bf2f((unsigned short)(v0 >> 16));
        }
    }
    const int c0 = lane * 2;
    const float mean0 = pSum[c0] * invN;
    const float var0  = pSq[c0] * invN - mean0 * mean0;
    const float sc0   = pG[c0] * rsqrtf(var0 + 1e-5f);
    const float sh0   = pB[c0] - mean0 * sc0;
    const float mean1 = pSum[c0 + 1] * invN;
    const float var1  = pSq[c0 + 1] * invN - mean1 * mean1;
    const float sc1   = pG[c0 + 1] * rsqrtf(var1 + 1e-5f);
    const float sh1   = pB[c0 + 1] - mean1 * sc1;
    const float dp1 = (float)(deg + 1);
    const float z0 = sc0 * a0 + dp1 * sh0;
    const float z1 = sc1 * a1 + dp1 * sh1;
    unsigned int o = ((unsigned int)f2bf(z1) << 16) | (unsigned int)f2bf(z0);
    *(unsigned int*)(Zb + (size_t)node * 128 + lane * 2) = o;
}

// ---------------- final: out = bn(t6) + h3 (fp32) --------------------------
__global__ void final_kernel(const unsigned short* __restrict__ t6,
                             const float* __restrict__ pSum, const float* __restrict__ pSq,
                             const float* __restrict__ pG, const float* __restrict__ pB,
                             const unsigned short* __restrict__ h3,
                             float* __restrict__ out, float invN, int total4)
{
    int idx = blockIdx.x * blockDim.x + threadIdx.x;
    if (idx >= total4) return;
    const int base = idx * 4;
    const int c0 = base & 127;
    ushort4 tv = *(const ushort4*)(t6 + base);
    ushort4 hv = *(const ushort4*)(h3 + base);
    unsigned short ts[4] = {tv.x, tv.y, tv.z, tv.w};
    unsigned short hs[4] = {hv.x, hv.y, hv.z, hv.w};
    float4 ov;
    float* po = &ov.x;
    #pragma unroll
    for (int j = 0; j < 4; ++j) {
        const int c = c0 + j;
        const float mean = pSum[c] * invN;
        const float var  = pSq[c] * invN - mean * mean;
        const float sc   = pG[c] * rsqrtf(var + 1e-5f);
        const float sh   = pB[c] - mean * sc;
        po[j] = sc * bf2f(ts[j]) + sh + bf2f(hs[j]);
    }
    *(float4*)(out + base) = ov;
}

// ---------------- weight pack: Wp[m][k] = bf16(W[k][m]) ---------------------
struct PackDesc { const float* src; unsigned short* dst; int K; int M; };
struct Pack7 { PackDesc d[7]; };
__global__ void pack_kernel(Pack7 p)
{
    PackDesc d = p.d[blockIdx.y];
    const int total = d.K * d.M;
    for (int idx = blockIdx.x * blockDim.x + threadIdx.x; idx < total;
         idx += gridDim.x * blockDim.x) {
        const int k = idx / d.M;
        const int m = idx - k * d.M;
        d.dst[(size_t)m * d.K + k] = f2bf(d.src[idx]);
    }
}

extern "C" void kernel_launch(void* const* d_in, const int* in_sizes, int n_in,
                              void* d_out, int out_size, void* d_ws, size_t ws_size,
                              hipStream_t stream)
{
    const float* x     = (const float*)d_in[0];
    const int*   ei    = (const int*)d_in[1];
    const float* enc_W = (const float*)d_in[2];
    const float* enc_b = (const float*)d_in[3];
    const float* bn_g  = (const float*)d_in[4];
    const float* bn_b  = (const float*)d_in[5];
    const float* gW1   = (const float*)d_in[6];
    const float* gb1   = (const float*)d_in[7];
    const float* gg    = (const float*)d_in[8];
    const float* gbb   = (const float*)d_in[9];
    const float* gW2   = (const float*)d_in[10];
    const float* gb2   = (const float*)d_in[11];
    const float* f2W1  = (const float*)d_in[12];
    const float* f2b1  = (const float*)d_in[13];
    const float* f2g1  = (const float*)d_in[14];
    const float* f2bb1 = (const float*)d_in[15];
    const float* f2W2  = (const float*)d_in[16];
    const float* f2b2  = (const float*)d_in[17];
    const float* f2g2  = (const float*)d_in[18];
    const float* f2bb2 = (const float*)d_in[19];
    const float* fnW1  = (const float*)d_in[20];
    const float* fnb1  = (const float*)d_in[21];
    const float* fng1  = (const float*)d_in[22];
    const float* fnbb1 = (const float*)d_in[23];
    const float* fnW2  = (const float*)d_in[24];
    const float* fnb2  = (const float*)d_in[25];
    const float* fng2  = (const float*)d_in[26];
    const float* fnbb2 = (const float*)d_in[27];

    const int D = 128;
    const int N = in_sizes[0] / D;   // 50000
    const int E = in_sizes[1] / 2;   // 640000
    const float invN = 1.0f / (float)N;

    // ---- workspace layout ----
    char* w = (char*)d_ws;
    float* s0 = (float*)w;          // [sum(128) | sq(128)]
    float* s1 = s0 + 256;
    float* s3 = s1 + 256;           // [sum(256) | sq(256)]
    float* s4 = s3 + 512;
    float* s5 = s4 + 256;           // [sum(512) | sq(512)]
    float* s6 = s5 + 1024;
    const size_t statsBytes = 2560 * sizeof(float);
    size_t off = statsBytes;

    unsigned short* wpE  = (unsigned short*)(w + off); off += (size_t)128 * 128 * 2;
    unsigned short* wpG1 = (unsigned short*)(w + off); off += (size_t)128 * 128 * 2;
    unsigned short* wpG2 = (unsigned short*)(w + off); off += (size_t)128 * 128 * 2;
    unsigned short* wpF1 = (unsigned short*)(w + off); off += (size_t)128 * 256 * 2;
    unsigned short* wpF2 = (unsigned short*)(w + off); off += (size_t)256 * 128 * 2;
    unsigned short* wpN1 = (unsigned short*)(w + off); off += (size_t)128 * 512 * 2;
    unsigned short* wpN2 = (unsigned short*)(w + off); off += (size_t)512 * 128 * 2;

    unsigned short* P1 = (unsigned short*)(w + off); off += (size_t)N * 128 * 2; // t0,t1,t4,t6
    unsigned short* Zb = (unsigned short*)(w + off); off += (size_t)N * 128 * 2; // Z, t2
    unsigned short* H3 = (unsigned short*)(w + off); off += (size_t)N * 128 * 2; // h3
    unsigned short* T3 = (unsigned short*)(w + off); off += (size_t)N * 256 * 2; // t3
    unsigned short* T5 = (unsigned short*)(w + off); off += (size_t)N * 512 * 2; // t5

    // CSR arrays inside T5 (CSR dead after gather; T5 first written later)
    const int NB = (N + 255) / 256;
    char* csr = (char*)T5;
    int* cnt    = (int*)csr;  csr += (size_t)NB * 256 * 4;
    int* offs   = (int*)csr;  csr += (size_t)NB * 256 * 4;
    int* cursor = (int*)csr;  csr += (size_t)NB * 256 * 4;
    int* blksum = (int*)csr;  csr += 1024;
    int* ssrc   = (int*)csr;

    hipMemsetAsync(d_ws, 0, statsBytes, stream);
    hipMemsetAsync(cnt, 0, (size_t)NB * 256 * 4, stream);

    Pack7 pk;
    pk.d[0] = PackDesc{enc_W, wpE, 128, 128};
    pk.d[1] = PackDesc{gW1, wpG1, 128, 128};
    pk.d[2] = PackDesc{gW2, wpG2, 128, 128};
    pk.d[3] = PackDesc{f2W1, wpF1, 128, 256};
    pk.d[4] = PackDesc{f2W2, wpF2, 256, 128};
    pk.d[5] = PackDesc{fnW1, wpN1, 128, 512};
    pk.d[6] = PackDesc{fnW2, wpN2, 512, 128};
    pack_kernel<<<dim3(64, 7), 256, 0, stream>>>(pk);

    const int eb = (E + 255) / 256;
    hist_kernel<<<eb, 256, 0, stream>>>(ei, cnt, E);
    scan_reduce<<<NB, 256, 0, stream>>>(cnt, blksum, N);
    scan_top<<<1, 256, 0, stream>>>(blksum, NB);
    scan_apply<<<NB, 256, 0, stream>>>(cnt, blksum, offs, cursor, N);
    place_kernel<<<eb, 256, 0, stream>>>(ei, cursor, ssrc, E);

    const int rb  = (N + 63) / 64;
    const int t4a = N * 128 / 4;
    const int ewb = (t4a + 255) / 256;

    // 1) t0 = x @ encW + enc_b                       -> P1, stats s0
    gemmf_kernel<128, 128, 1><<<rb, 256, 0, stream>>>(
        x, nullptr, nullptr, nullptr, nullptr,
        wpE, enc_b, s0, s0 + 128, P1, N, invN);
    // 2) Z = bn0(t0 self+agg)                        -> Zb
    gather_kernel<<<(N + 3) / 4, 256, 0, stream>>>(
        P1, s0, s0 + 128, bn_g, bn_b, invN, ssrc, offs, cnt, Zb, N);
    // 3) t1 = Z @ gW1 + gb1                          -> P1, stats s1
    gemmf_kernel<128, 128, 0><<<rb, 256, 0, stream>>>(
        Zb, nullptr, nullptr, nullptr, nullptr,
        wpG1, gb1, s1, s1 + 128, P1, N, invN);
    // 4) t2 = gelu(bn(t1)) @ gW2 + gb2               -> Zb (no stats)
    gemmf_kernel<128, 128, 2><<<rb, 256, 0, stream>>>(
        P1, s1, s1 + 128, gg, gbb,
        wpG2, gb2, nullptr, nullptr, Zb, N, invN);
    // 5) t3 = t2 @ f2W1 + f2b1                       -> T3 [N,256], stats s3
    gemmf_kernel<128, 256, 0><<<rb, 256, 0, stream>>>(
        Zb, nullptr, nullptr, nullptr, nullptr,
        wpF1, f2b1, s3, s3 + 256, T3, N, invN);
    // 6) t4 = gelu(bn(t3)) @ f2W2 + f2b2             -> P1, stats s4
    gemmf_kernel<256, 128, 2><<<rb, 256, 0, stream>>>(
        T3, s3, s3 + 256, f2g1, f2bb1,
        wpF2, f2b2, s4, s4 + 128, P1, N, invN);
    // 7) h3 = bn(t4) + t2 + x                        -> H3 (bf16, once)
    h3_kernel<<<ewb, 256, 0, stream>>>(
        P1, s4, s4 + 128, f2g2, f2bb2, Zb, x, H3, invN, t4a);
    // 8) t5 = h3 @ fnW1 + fnb1                       -> T5 [N,512], stats s5
    gemmf_kernel<128, 512, 0><<<rb, 256, 0, stream>>>(
        H3, nullptr, nullptr, nullptr, nullptr,
        wpN1, fnb1, s5, s5 + 512, T5, N, invN);
    // 9) t6 = gelu(bn(t5)) @ fnW2 + fnb2             -> P1, stats s6
    gemmf_kernel<512, 128, 2><<<rb, 256, 0, stream>>>(
        T5, s5, s5 + 512, fng1, fnbb1,
        wpN2, fnb2, s6, s6 + 128, P1, N, invN);
    // 10) out = bn(t6) + h3                           -> d_out (fp32)
    final_kernel<<<ewb, 256, 0, stream>>>(
        P1, s6, s6 + 128, fng2, fnbb2, H3, (float*)d_out, invN, t4a);

    (void)n_in; (void)out_size; (void)ws_size;
}